// Round 1
// baseline (451.005 us; speedup 1.0000x reference)
//
#include <hip/hip_runtime.h>

#define BATCH 524288
#define D 16
#define NSYS 32
#define HID 128

__global__ __launch_bounds__(256) void andp_fused_fp32(
    const float* __restrict__ x_cur,   // [B,16]
    const float* __restrict__ W1,      // [128,16]
    const float* __restrict__ b1,      // [128]
    const float* __restrict__ W2,      // [32,128]
    const float* __restrict__ b2,      // [32]
    const float* __restrict__ Bm,      // [32,16,16]
    const float* __restrict__ Cm,      // [32,16,16]
    const float* __restrict__ x_t,     // [16]
    float* __restrict__ out)           // [B,16]
{
    const int b = blockIdx.x * blockDim.x + threadIdx.x;

    // ---- load my row (contiguous 64B, vectorized) ----
    float x[D];
    {
        const float4* xr = reinterpret_cast<const float4*>(x_cur + (size_t)b * D);
        float4 v0 = xr[0], v1 = xr[1], v2 = xr[2], v3 = xr[3];
        x[0]=v0.x; x[1]=v0.y; x[2]=v0.z; x[3]=v0.w;
        x[4]=v1.x; x[5]=v1.y; x[6]=v1.z; x[7]=v1.w;
        x[8]=v2.x; x[9]=v2.y; x[10]=v2.z; x[11]=v2.w;
        x[12]=v3.x; x[13]=v3.y; x[14]=v3.z; x[15]=v3.w;
    }

    // ---- gating MLP: logits = W2 @ relu(W1 @ x + b1) + b2 ----
    float l[NSYS];
#pragma unroll
    for (int n = 0; n < NSYS; ++n) l[n] = b2[n];

#pragma unroll 2
    for (int j = 0; j < HID; ++j) {
        float hj = b1[j];
#pragma unroll
        for (int d = 0; d < D; ++d) hj = fmaf(x[d], W1[j * D + d], hj);
        hj = fmaxf(hj, 0.0f);
#pragma unroll
        for (int n = 0; n < NSYS; ++n) l[n] = fmaf(hj, W2[n * HID + j], l[n]);
    }

    // ---- softmax over n ----
    float m = l[0];
#pragma unroll
    for (int n = 1; n < NSYS; ++n) m = fmaxf(m, l[n]);
    float s = 0.0f;
#pragma unroll
    for (int n = 0; n < NSYS; ++n) { l[n] = __expf(l[n] - m); s += l[n]; }
    float inv = 1.0f / s;
#pragma unroll
    for (int n = 0; n < NSYS; ++n) l[n] *= inv;

    // ---- diff = x_target - x ----
    float df[D];
#pragma unroll
    for (int d = 0; d < D; ++d) df[d] = x_t[d] - x[d];

    // ---- out[k] = sum_n w[n] * sum_d (Bm+Cm)[n,k,d] * diff[d] ----
    float o[D];
#pragma unroll
    for (int k = 0; k < D; ++k) o[k] = 0.0f;

    for (int n = 0; n < NSYS; ++n) {
        const float wn = l[n];
        const float* __restrict__ Bn = Bm + n * D * D;
        const float* __restrict__ Cn = Cm + n * D * D;
#pragma unroll
        for (int k = 0; k < D; ++k) {
            float t = 0.0f;
#pragma unroll
            for (int d = 0; d < D; ++d)
                t = fmaf(Bn[k * D + d] + Cn[k * D + d], df[d], t);
            o[k] = fmaf(wn, t, o[k]);
        }
    }

    // ---- store (contiguous 64B, vectorized) ----
    {
        float4* orow = reinterpret_cast<float4*>(out + (size_t)b * D);
        orow[0] = make_float4(o[0], o[1], o[2], o[3]);
        orow[1] = make_float4(o[4], o[5], o[6], o[7]);
        orow[2] = make_float4(o[8], o[9], o[10], o[11]);
        orow[3] = make_float4(o[12], o[13], o[14], o[15]);
    }
}

extern "C" void kernel_launch(void* const* d_in, const int* in_sizes, int n_in,
                              void* d_out, int out_size, void* d_ws, size_t ws_size,
                              hipStream_t stream) {
    const float* x_cur = (const float*)d_in[0];
    const float* W1    = (const float*)d_in[1];
    const float* b1    = (const float*)d_in[2];
    const float* W2    = (const float*)d_in[3];
    const float* b2    = (const float*)d_in[4];
    const float* Bm    = (const float*)d_in[5];
    const float* Cm    = (const float*)d_in[6];
    const float* x_t   = (const float*)d_in[7];
    float* out = (float*)d_out;

    const int threads = 256;
    const int blocks = BATCH / threads;  // 524288 / 256 = 2048
    andp_fused_fp32<<<blocks, threads, 0, stream>>>(
        x_cur, W1, b1, W2, b2, Bm, Cm, x_t, out);
}

// Round 2
// 157.415 us; speedup vs baseline: 2.8651x; 2.8651x over previous
//
#include <hip/hip_runtime.h>

#define D 16
#define HID 128
#define NSYS 32

typedef short short8 __attribute__((ext_vector_type(8)));
typedef __bf16 bf16x8 __attribute__((ext_vector_type(8)));
typedef float f32x4 __attribute__((ext_vector_type(4)));

__device__ __forceinline__ short f2bf(float f) {
    union { float f; unsigned u; } v; v.f = f;
    unsigned r = (v.u + 0x7fffu + ((v.u >> 16) & 1u)) >> 16;
    return (short)r;
}

__device__ __forceinline__ bf16x8 s2b(short8 s) {
    return __builtin_bit_cast(bf16x8, s);
}

// LDS layout (bytes):
//   sW1  @     0:  128x24 bf16 (row h, stride 24)          6144
//   sW2  @  6144:   32x136 bf16 (row n, stride 136)        8704
//   sA2  @ 14848:   16x520 bf16 (row k_out, stride 520)   16640
//   sB1  @ 31488:  128 f32                                  512
//   sB2  @ 32000:   32 f32                                  128
//   sXT  @ 32128:   16 f32                                   64
//   sX   @ 32192:  per-wave 32x20 f32 (stride 20)       4x2560
//   sHS  @ 42432:  per-wave 32x136 bf16 (stride 136)    4x8704  [aliased as 32x33 f32 softmax w]
// total 77248 -> 2 blocks/CU
#define SMEM_BYTES 77248

__global__ __launch_bounds__(256, 2) void andp_mfma(
    const float* __restrict__ x_cur,
    const float* __restrict__ W1,
    const float* __restrict__ b1,
    const float* __restrict__ W2,
    const float* __restrict__ b2,
    const float* __restrict__ Bm,
    const float* __restrict__ Cm,
    const float* __restrict__ x_t,
    float* __restrict__ out)
{
    extern __shared__ char smem[];
    short* sW1 = (short*)(smem);
    short* sW2 = (short*)(smem + 6144);
    short* sA2 = (short*)(smem + 14848);
    float* sB1 = (float*)(smem + 31488);
    float* sB2 = (float*)(smem + 32000);
    float* sXT = (float*)(smem + 32128);

    const int tid = threadIdx.x;

    // ---- phase 0: stage weights into LDS (bf16), A = Bm + Cm pre-added, pre-transposed ----
#pragma unroll
    for (int i = 0; i < 8; ++i) {            // W1: 2048 elems, [h][d] native
        int idx = tid + i * 256;
        sW1[(idx >> 4) * 24 + (idx & 15)] = f2bf(W1[idx]);
    }
#pragma unroll
    for (int i = 0; i < 16; ++i) {           // W2: 4096 elems, [n][h] native
        int idx = tid + i * 256;
        sW2[(idx >> 7) * 136 + (idx & 127)] = f2bf(W2[idx]);
    }
#pragma unroll
    for (int i = 0; i < 32; ++i) {           // A2T[k][n*16+d] = Bm[n][k][d] + Cm[n][k][d]
        int idx = tid + i * 256;
        int n = idx >> 8, k = (idx >> 4) & 15, d = idx & 15;
        sA2[k * 520 + n * 16 + d] = f2bf(Bm[idx] + Cm[idx]);
    }
    if (tid < HID)  sB1[tid] = b1[tid];
    if (tid < NSYS) sB2[tid] = b2[tid];
    if (tid < D)    sXT[tid] = x_t[tid];
    __syncthreads();

    const int wave = tid >> 6;
    const int lane = tid & 63;
    const int c = lane & 15;      // m for A-frags / n for B-frags / col for C
    const int q = lane >> 4;      // quad

    float* xsw = (float*)(smem + 32192 + wave * 2560);
    short* hsw = (short*)(smem + 42432 + wave * 8704);
    float* wsw = (float*)hsw;     // alias: softmax weights after hs is dead

    // per-lane constant preloads
    float b1v[8];
#pragma unroll
    for (int t = 0; t < 8; ++t) b1v[t] = sB1[t * 16 + c];
    const float b2v0 = sB2[c], b2v1 = sB2[16 + c];
    const int d0 = (q & 1) * 8;
    float xtq[8];
#pragma unroll
    for (int j = 0; j < 8; ++j) xtq[j] = sXT[d0 + j];

    const int blk_row = blockIdx.x * 256 + wave * 64;

    for (int p = 0; p < 2; ++p) {
        const int r0 = blk_row + p * 32;   // 32 rows this pair (two 16-row M-tiles)

        // ---- phase 1: load x tile [32 x 16] f32 -> xsw (stride 20) ----
        {
            const float4* g = (const float4*)(x_cur + (size_t)r0 * D);
#pragma unroll
            for (int i = 0; i < 2; ++i) {
                int fi = lane + i * 64;            // float4 index 0..127
                float4 v = g[fi];
                int row = fi >> 2, col = (fi & 3) * 4;
                float* dst = &xsw[row * 20 + col];
                dst[0] = v.x; dst[1] = v.y; dst[2] = v.z; dst[3] = v.w;
            }
        }

        // ---- phase 2: GEMM1  h[32,128] = x @ W1^T  (K=16 padded to 32) ----
        bf16x8 afr[2];
#pragma unroll
        for (int t01 = 0; t01 < 2; ++t01) {
            short8 a;
            if (q < 2) {
                const float* xr = &xsw[(t01 * 16 + c) * 20 + q * 8];
#pragma unroll
                for (int j = 0; j < 8; ++j) a[j] = f2bf(xr[j]);
            } else {
#pragma unroll
                for (int j = 0; j < 8; ++j) a[j] = 0;
            }
            afr[t01] = s2b(a);
        }
        f32x4 acc1[2][8];
#pragma unroll
        for (int t = 0; t < 8; ++t) {
            short8 b;
            if (q < 2) b = *(const short8*)&sW1[(t * 16 + c) * 24 + q * 8];
            else { short8 z = {0,0,0,0,0,0,0,0}; b = z; }
            f32x4 z4 = {0.f, 0.f, 0.f, 0.f};
            bf16x8 bb = s2b(b);
            acc1[0][t] = __builtin_amdgcn_mfma_f32_16x16x32_bf16(afr[0], bb, z4, 0, 0, 0);
            acc1[1][t] = __builtin_amdgcn_mfma_f32_16x16x32_bf16(afr[1], bb, z4, 0, 0, 0);
        }
        // epilogue: bias + relu -> hsw (C layout: row = q*4+r, col = t*16+c)
#pragma unroll
        for (int t01 = 0; t01 < 2; ++t01)
#pragma unroll
            for (int t = 0; t < 8; ++t)
#pragma unroll
                for (int r = 0; r < 4; ++r) {
                    float v = acc1[t01][t][r] + b1v[t];
                    v = fmaxf(v, 0.f);
                    hsw[(t01 * 16 + q * 4 + r) * 136 + t * 16 + c] = f2bf(v);
                }

        // ---- phase 3: GEMM2  logits[32,32] = h @ W2^T  (K=128) ----
        f32x4 acc2[2][2];
        {
            f32x4 z4 = {0.f, 0.f, 0.f, 0.f};
            acc2[0][0] = z4; acc2[0][1] = z4; acc2[1][0] = z4; acc2[1][1] = z4;
        }
#pragma unroll
        for (int kk = 0; kk < 4; ++kk) {
            bf16x8 a0 = s2b(*(const short8*)&hsw[c * 136 + kk * 32 + q * 8]);
            bf16x8 a1 = s2b(*(const short8*)&hsw[(16 + c) * 136 + kk * 32 + q * 8]);
#pragma unroll
            for (int t2 = 0; t2 < 2; ++t2) {
                bf16x8 b = s2b(*(const short8*)&sW2[(t2 * 16 + c) * 136 + kk * 32 + q * 8]);
                acc2[0][t2] = __builtin_amdgcn_mfma_f32_16x16x32_bf16(a0, b, acc2[0][t2], 0, 0, 0);
                acc2[1][t2] = __builtin_amdgcn_mfma_f32_16x16x32_bf16(a1, b, acc2[1][t2], 0, 0, 0);
            }
        }

        // ---- phase 4: softmax over 32 systems, per row -> wsw (aliases hsw; hs fully consumed) ----
#pragma unroll
        for (int t01 = 0; t01 < 2; ++t01) {
#pragma unroll
            for (int r = 0; r < 4; ++r) {
                float v0 = acc2[t01][0][r] + b2v0;
                float v1 = acc2[t01][1][r] + b2v1;
                float mx = fmaxf(v0, v1);
                mx = fmaxf(mx, __shfl_xor(mx, 1, 64));
                mx = fmaxf(mx, __shfl_xor(mx, 2, 64));
                mx = fmaxf(mx, __shfl_xor(mx, 4, 64));
                mx = fmaxf(mx, __shfl_xor(mx, 8, 64));
                float e0 = __expf(v0 - mx);
                float e1 = __expf(v1 - mx);
                float s = e0 + e1;
                s += __shfl_xor(s, 1, 64);
                s += __shfl_xor(s, 2, 64);
                s += __shfl_xor(s, 4, 64);
                s += __shfl_xor(s, 8, 64);
                float inv = 1.0f / s;
                int row = t01 * 16 + q * 4 + r;
                wsw[row * 33 + c]      = e0 * inv;
                wsw[row * 33 + 16 + c] = e1 * inv;
            }
        }

        // ---- phase 5: GEMM3  out[32,16] = P @ A2, P[m][n*16+d] = w[m][n]*diff[m][d] (K=512) ----
        float dif[2][8];
#pragma unroll
        for (int t01 = 0; t01 < 2; ++t01) {
            const float* xr = &xsw[(t01 * 16 + c) * 20 + d0];
#pragma unroll
            for (int j = 0; j < 8; ++j) dif[t01][j] = xtq[j] - xr[j];
        }
        f32x4 acc3[2];
        { f32x4 z4 = {0.f, 0.f, 0.f, 0.f}; acc3[0] = z4; acc3[1] = z4; }
        const int qh = q >> 1;
#pragma unroll
        for (int kk = 0; kk < 16; ++kk) {
            int ns = 2 * kk + qh;                    // system index for this quad's k-slice
            float w0 = wsw[c * 33 + ns];
            float w1 = wsw[(16 + c) * 33 + ns];
            bf16x8 b = s2b(*(const short8*)&sA2[c * 520 + kk * 32 + q * 8]);
            short8 a0s, a1s;
#pragma unroll
            for (int j = 0; j < 8; ++j) {
                a0s[j] = f2bf(w0 * dif[0][j]);
                a1s[j] = f2bf(w1 * dif[1][j]);
            }
            acc3[0] = __builtin_amdgcn_mfma_f32_16x16x32_bf16(s2b(a0s), b, acc3[0], 0, 0, 0);
            acc3[1] = __builtin_amdgcn_mfma_f32_16x16x32_bf16(s2b(a1s), b, acc3[1], 0, 0, 0);
        }

        // ---- store (C layout: row = q*4+r, col = c) ----
#pragma unroll
        for (int t01 = 0; t01 < 2; ++t01) {
            int rowg = r0 + t01 * 16 + q * 4;
            float* op = out + (size_t)rowg * D + c;
#pragma unroll
            for (int r = 0; r < 4; ++r) op[(size_t)r * D] = acc3[t01][r];
        }
    }
}

extern "C" void kernel_launch(void* const* d_in, const int* in_sizes, int n_in,
                              void* d_out, int out_size, void* d_ws, size_t ws_size,
                              hipStream_t stream) {
    const float* x_cur = (const float*)d_in[0];
    const float* W1    = (const float*)d_in[1];
    const float* b1    = (const float*)d_in[2];
    const float* W2    = (const float*)d_in[3];
    const float* b2    = (const float*)d_in[4];
    const float* Bm    = (const float*)d_in[5];
    const float* Cm    = (const float*)d_in[6];
    const float* x_t   = (const float*)d_in[7];
    float* out = (float*)d_out;

    const int blocks = 524288 / 256;   // 2048 blocks x 256 rows
    andp_mfma<<<blocks, 256, SMEM_BYTES, stream>>>(
        x_cur, W1, b1, W2, b2, Bm, Cm, x_t, out);
}

// Round 3
// 134.300 us; speedup vs baseline: 3.3582x; 1.1721x over previous
//
#include <hip/hip_runtime.h>

#define BATCH 524288

typedef __bf16 bf16x8 __attribute__((ext_vector_type(8)));
typedef float f32x4 __attribute__((ext_vector_type(4)));
typedef float f32x8 __attribute__((ext_vector_type(8)));

// LDS: sA2 @ 0: 16 rows x 520 bf16 = 16640 B  (A2T[k_out][n*16+d], +8 bf16 row pad)
//      per-wave h  @ 16640 + wave*8704: 32 x 136 bf16 (row = batch row, col = hidden)
//      per-wave w  aliases h base: 32 x 33 f32 (4224 B; disjoint from h rows 16..31 @ >=4352)
#define SMEM_BYTES (16640 + 4 * 8704)   // 51456 B -> 3 blocks/CU

__device__ __forceinline__ f32x8 load8(const float* __restrict__ p) {
    float4 a = *(const float4*)p;
    float4 b = *(const float4*)(p + 4);
    f32x8 v = {a.x, a.y, a.z, a.w, b.x, b.y, b.z, b.w};
    return v;
}

__global__ __launch_bounds__(256, 3) void andp_v3(
    const float* __restrict__ x_cur,
    const float* __restrict__ W1,
    const float* __restrict__ b1,
    const float* __restrict__ W2,
    const float* __restrict__ b2,
    const float* __restrict__ Bm,
    const float* __restrict__ Cm,
    const float* __restrict__ x_t,
    float* __restrict__ out)
{
    extern __shared__ char smem[];
    __bf16* sA2 = (__bf16*)smem;
    const int tid = threadIdx.x;

    // ---- stage A2 = Bm + Cm, transposed: sA2[k][n*16+d] = A[n][k][d] ----
#pragma unroll
    for (int i = 0; i < 32; ++i) {
        int idx = tid + i * 256;
        int n = idx >> 8, k = (idx >> 4) & 15, d = idx & 15;
        sA2[k * 520 + n * 16 + d] = (__bf16)(Bm[idx] + Cm[idx]);
    }

    const int wave = tid >> 6, lane = tid & 63;
    const int c = lane & 15, q = lane >> 4;
    const int qh = q >> 1;            // n-parity for G3 k-slice
    const int hh = (q & 1) * 8;       // d-half this lane owns

    __bf16* hsw = (__bf16*)(smem + 16640 + wave * 8704);
    float*  wsw = (float*)hsw;        // alias (disjoint byte ranges, see header)

    // ---- one-time register fragments ----
    bf16x8 w1f[8];                    // G1 B-op: W1^T[k=q*8+j][h=t*16+c], zero for q>=2 (K pad)
#pragma unroll
    for (int t = 0; t < 8; ++t) {
        f32x8 v = {0.f,0.f,0.f,0.f,0.f,0.f,0.f,0.f};
        if (q < 2) v = load8(W1 + (t * 16 + c) * 16 + q * 8);
        w1f[t] = __builtin_convertvector(v, bf16x8);
    }
    bf16x8 w2f[2][4];                 // G2 A-op: W2[n=t2*16+c][k=kk*32+q*8+j]
#pragma unroll
    for (int t2 = 0; t2 < 2; ++t2)
#pragma unroll
        for (int kk = 0; kk < 4; ++kk)
            w2f[t2][kk] = __builtin_convertvector(
                load8(W2 + (t2 * 16 + c) * 128 + kk * 32 + q * 8), bf16x8);

    float b1v[8];
#pragma unroll
    for (int t = 0; t < 8; ++t) b1v[t] = b1[t * 16 + c];
    float b2v[2][4];
#pragma unroll
    for (int t2 = 0; t2 < 2; ++t2)
#pragma unroll
        for (int r = 0; r < 4; ++r) b2v[t2][r] = b2[t2 * 16 + q * 4 + r];
    const f32x8 xtv = load8(x_t + hh);

    __syncthreads();

    const int blk_row = blockIdx.x * 256 + wave * 64;
    const f32x4 z4 = {0.f, 0.f, 0.f, 0.f};

    for (int p = 0; p < 2; ++p) {
        const int r0 = blk_row + p * 32;

        // ---- x direct from global in fragment layout; serves G1 A-frag and G3 diff ----
        bf16x8 af[2];
        f32x8 dif[2];
#pragma unroll
        for (int t01 = 0; t01 < 2; ++t01) {
            f32x8 xv = load8(x_cur + (size_t)(r0 + t01 * 16 + c) * 16 + hh);
            af[t01]  = __builtin_convertvector(xv, bf16x8);  // q>=2 garbage * zero W1 = 0
            dif[t01] = xtv - xv;
        }

#pragma unroll
        for (int t01 = 0; t01 < 2; ++t01) {
            // ---- G1: h[16,128] = x @ W1^T (K=16 padded to 32) ----
            f32x4 acc1[8];
#pragma unroll
            for (int t = 0; t < 8; ++t)
                acc1[t] = __builtin_amdgcn_mfma_f32_16x16x32_bf16(af[t01], w1f[t], z4, 0, 0, 0);
            // epilogue: bias+relu -> hsw[row = t01*16+q*4+r][h = t*16+c]
#pragma unroll
            for (int t = 0; t < 8; ++t)
#pragma unroll
                for (int r = 0; r < 4; ++r) {
                    float v = fmaxf(acc1[t][r] + b1v[t], 0.f);
                    hsw[(t01 * 16 + q * 4 + r) * 136 + t * 16 + c] = (__bf16)v;
                }

            // ---- G2 (transposed): logitsT[32n, 16rows] = W2 @ h^T, K=128 ----
            f32x4 acc2[2];
            acc2[0] = z4; acc2[1] = z4;
#pragma unroll
            for (int kk = 0; kk < 4; ++kk) {
                bf16x8 hb = *(const bf16x8*)(hsw + (t01 * 16 + c) * 136 + kk * 32 + q * 8);
                acc2[0] = __builtin_amdgcn_mfma_f32_16x16x32_bf16(w2f[0][kk], hb, acc2[0], 0, 0, 0);
                acc2[1] = __builtin_amdgcn_mfma_f32_16x16x32_bf16(w2f[1][kk], hb, acc2[1], 0, 0, 0);
            }

            // ---- softmax over n: lane holds n = t2*16+q*4+r for data-row t01*16+c ----
            float l[8];
#pragma unroll
            for (int t2 = 0; t2 < 2; ++t2)
#pragma unroll
                for (int r = 0; r < 4; ++r) l[t2 * 4 + r] = acc2[t2][r] + b2v[t2][r];
            float mx = l[0];
#pragma unroll
            for (int i = 1; i < 8; ++i) mx = fmaxf(mx, l[i]);
            mx = fmaxf(mx, __shfl_xor(mx, 16, 64));
            mx = fmaxf(mx, __shfl_xor(mx, 32, 64));
            float e[8], s = 0.f;
#pragma unroll
            for (int i = 0; i < 8; ++i) { e[i] = __expf(l[i] - mx); s += e[i]; }
            s += __shfl_xor(s, 16, 64);
            s += __shfl_xor(s, 32, 64);
            float inv = 1.0f / s;
#pragma unroll
            for (int t2 = 0; t2 < 2; ++t2)
#pragma unroll
                for (int r = 0; r < 4; ++r)
                    wsw[(t01 * 16 + c) * 33 + t2 * 16 + q * 4 + r] = e[t2 * 4 + r] * inv;
        }

        // ---- G3: out[32,16] = G @ A2, G[row, n*16+d] = w[row,n]*dif[row,d], K=512 ----
        f32x4 acc3[2];
        acc3[0] = z4; acc3[1] = z4;
#pragma unroll
        for (int kk = 0; kk < 16; ++kk) {
            float w0 = wsw[c * 33 + 2 * kk + qh];          // row c      (t01=0)
            float w1 = wsw[(16 + c) * 33 + 2 * kk + qh];   // row 16+c   (t01=1)
            bf16x8 bfr = *(const bf16x8*)(sA2 + c * 520 + kk * 32 + q * 8);
            bf16x8 a0 = __builtin_convertvector(dif[0] * w0, bf16x8);
            bf16x8 a1 = __builtin_convertvector(dif[1] * w1, bf16x8);
            acc3[0] = __builtin_amdgcn_mfma_f32_16x16x32_bf16(a0, bfr, acc3[0], 0, 0, 0);
            acc3[1] = __builtin_amdgcn_mfma_f32_16x16x32_bf16(a1, bfr, acc3[1], 0, 0, 0);
        }

        // ---- store: C layout row = q*4+r, col = c ----
#pragma unroll
        for (int t01 = 0; t01 < 2; ++t01) {
            float* op = out + (size_t)(r0 + t01 * 16 + q * 4) * 16 + c;
#pragma unroll
            for (int r = 0; r < 4; ++r) op[r * 16] = acc3[t01][r];
        }
    }
}

extern "C" void kernel_launch(void* const* d_in, const int* in_sizes, int n_in,
                              void* d_out, int out_size, void* d_ws, size_t ws_size,
                              hipStream_t stream) {
    const float* x_cur = (const float*)d_in[0];
    const float* W1    = (const float*)d_in[1];
    const float* b1    = (const float*)d_in[2];
    const float* W2    = (const float*)d_in[3];
    const float* b2    = (const float*)d_in[4];
    const float* Bm    = (const float*)d_in[5];
    const float* Cm    = (const float*)d_in[6];
    const float* x_t   = (const float*)d_in[7];
    float* out = (float*)d_out;

    const int blocks = BATCH / 256;   // 2048 blocks x 256 rows
    andp_v3<<<blocks, 256, SMEM_BYTES, stream>>>(
        x_cur, W1, b1, W2, b2, Bm, Cm, x_t, out);
}